// Round 1
// baseline (2026.094 us; speedup 1.0000x reference)
//
#include <hip/hip_runtime.h>
#include <math.h>

// ---- static problem dims ----
#define NT_   9216          // B*L tokens
#define D_    256
#define NH_   8
#define HD_   32
#define L_    2304
#define HH_   48
#define WW_   48
#define MLP_  1024
#define NL_   4

// =====================================================================
// helpers
// =====================================================================
__device__ __forceinline__ float gelu_tanh(float x) {
    // matches jax.nn.gelu(approximate=True)
    const float c0 = 0.7978845608028654f;   // sqrt(2/pi)
    const float c1 = 0.044715f;
    float u = c0 * (x + c1 * x * x * x);
    return 0.5f * x * (1.0f + tanhf(u));
}

// =====================================================================
// embed: h[t][d] = x*Win[0][d] + yn*Win[1][d] + xn*Win[2][d] + b_in[d]
// grid: NT_ blocks x 256 threads
// =====================================================================
__global__ void embed_kernel(const int* __restrict__ x, const float* __restrict__ Win,
                             const float* __restrict__ b_in, float* __restrict__ h) {
    int t = blockIdx.x, d = threadIdx.x;
    int l = t % L_;
    int yy = l / WW_, xx = l % WW_;
    float xv = (float)x[t];
    float yn = yy * (1.0f / 47.0f);
    float xn = xx * (1.0f / 47.0f);
    h[t * D_ + d] = xv * Win[d] + yn * Win[D_ + d] + xn * Win[2 * D_ + d] + b_in[d];
}

// =====================================================================
// LayerNorm: y[t][d] = (h-mu)*rsqrt(var+eps)*s[d] + b[d]
// grid: NT_ blocks x 256 threads (one token per block)
// =====================================================================
__global__ void ln_kernel(const float* __restrict__ h, const float* __restrict__ s,
                          const float* __restrict__ bb, float* __restrict__ y) {
    int t = blockIdx.x, d = threadIdx.x;
    float v = h[t * D_ + d];
    float a = v, b2 = v * v;
    #pragma unroll
    for (int off = 32; off; off >>= 1) {
        a  += __shfl_xor(a,  off);
        b2 += __shfl_xor(b2, off);
    }
    __shared__ float red[8];
    int wave = threadIdx.x >> 6;
    if ((threadIdx.x & 63) == 0) { red[wave] = a; red[4 + wave] = b2; }
    __syncthreads();
    float sum   = red[0] + red[1] + red[2] + red[3];
    float sumsq = red[4] + red[5] + red[6] + red[7];
    float mu  = sum * (1.0f / D_);
    float var = sumsq * (1.0f / D_) - mu * mu;
    float rs  = rsqrtf(var + 1e-6f);
    y[t * D_ + d] = (v - mu) * rs * s[d] + bb[d];
}

// =====================================================================
// local attention: 25-neighbor torus window, radius 2.
// one block per token: 256 threads = 8 heads x 32 lanes.
// Masked (-1e9) entries underflow to exactly 0 in the reference softmax,
// so summing only the 25 allowed neighbors is exact.
// =====================================================================
__global__ void attn_kernel(const float* __restrict__ q, const float* __restrict__ k,
                            const float* __restrict__ v, const float* __restrict__ rel_emb,
                            float* __restrict__ att) {
    int t = blockIdx.x;
    int hh = threadIdx.x >> 5;      // head 0..7
    int e  = threadIdx.x & 31;      // dim within head
    int b  = t / L_;
    int l  = t - b * L_;
    int yy = l / WW_, xx = l - yy * WW_;

    float qv = q[t * D_ + hh * HD_ + e];
    const float scale = 0.17677669529663687f;  // 1/sqrt(32)

    float scores[25];
    int   nidx[25];
    #pragma unroll
    for (int oy = -2; oy <= 2; ++oy) {
        #pragma unroll
        for (int ox = -2; ox <= 2; ++ox) {
            int j = (oy + 2) * 5 + (ox + 2);
            int ny = yy + oy; ny += (ny < 0) ? HH_ : 0; ny -= (ny >= HH_) ? HH_ : 0;
            int nx = xx + ox; nx += (nx < 0) ? WW_ : 0; nx -= (nx >= WW_) ? WW_ : 0;
            int nt = b * L_ + ny * WW_ + nx;
            nidx[j] = nt;
            float kv = k[nt * D_ + hh * HD_ + e];
            float dot = qv * kv;
            #pragma unroll
            for (int off = 16; off; off >>= 1) dot += __shfl_xor(dot, off, 32);
            // dy = qy-ky = -oy (shortest signed, |oy|<=2), bucket = clip+7 = 7-oy
            float bias = rel_emb[hh * 225 + (7 - oy) * 15 + (7 - ox)];
            scores[j] = dot * scale + bias;
        }
    }
    float m = scores[0];
    #pragma unroll
    for (int j = 1; j < 25; ++j) m = fmaxf(m, scores[j]);
    float sum = 0.0f;
    #pragma unroll
    for (int j = 0; j < 25; ++j) { scores[j] = expf(scores[j] - m); sum += scores[j]; }
    float inv = 1.0f / sum;
    float acc = 0.0f;
    #pragma unroll
    for (int j = 0; j < 25; ++j) acc += scores[j] * v[nidx[j] * D_ + hh * HD_ + e];
    att[t * D_ + hh * HD_ + e] = acc * inv;
}

// =====================================================================
// fp32 tiled GEMM: C[M,N] = A[M,K] @ B[K,N] + bias[N]  (+gelu) (+res)
// BM=BN=64, BK=16, 256 threads (16x16), 4x4 per thread.
// M%64==0, N%64==0, K%16==0 guaranteed by problem dims.
// =====================================================================
template<bool GELU, bool RES>
__global__ void gemm_kernel(const float* __restrict__ A, const float* __restrict__ Bw,
                            const float* __restrict__ bias, const float* res,
                            float* C, int M, int N, int K) {
    __shared__ float As[16][68];   // [kk][m], stride 68 floats keeps 16B alignment
    __shared__ float Bs[16][68];   // [kk][n]
    int bm = blockIdx.y * 64, bn = blockIdx.x * 64;
    int tx = threadIdx.x & 15, ty = threadIdx.x >> 4;

    float acc[4][4] = {};
    for (int k0 = 0; k0 < K; k0 += 16) {
        #pragma unroll
        for (int i = threadIdx.x; i < 64 * 16; i += 256) {
            int m = i >> 4, kk = i & 15;
            As[kk][m] = A[(bm + m) * K + k0 + kk];
        }
        #pragma unroll
        for (int i = threadIdx.x; i < 16 * 64; i += 256) {
            int kk = i >> 6, n = i & 63;
            Bs[kk][n] = Bw[(k0 + kk) * N + bn + n];
        }
        __syncthreads();
        #pragma unroll
        for (int kk = 0; kk < 16; ++kk) {
            float4 av = *(const float4*)&As[kk][ty * 4];
            float4 bv = *(const float4*)&Bs[kk][tx * 4];
            float a4[4] = {av.x, av.y, av.z, av.w};
            float b4[4] = {bv.x, bv.y, bv.z, bv.w};
            #pragma unroll
            for (int i = 0; i < 4; ++i)
                #pragma unroll
                for (int j = 0; j < 4; ++j)
                    acc[i][j] += a4[i] * b4[j];
        }
        __syncthreads();
    }
    #pragma unroll
    for (int i = 0; i < 4; ++i) {
        int m = bm + ty * 4 + i;
        #pragma unroll
        for (int j = 0; j < 4; ++j) {
            int n = bn + tx * 4 + j;
            float vv = acc[i][j] + bias[n];
            if (GELU) vv = gelu_tanh(vv);
            if (RES)  vv += res[m * N + n];
            C[m * N + n] = vv;
        }
    }
}

// =====================================================================
// final: fused LN(lnF) + dot with Wout + bout -> logits[t]
// one block per token
// =====================================================================
__global__ void final_kernel(const float* __restrict__ h, const float* __restrict__ s,
                             const float* __restrict__ bb, const float* __restrict__ Wout,
                             const float* __restrict__ bout, float* __restrict__ out) {
    int t = blockIdx.x, d = threadIdx.x;
    float v = h[t * D_ + d];
    float a = v, b2 = v * v;
    #pragma unroll
    for (int off = 32; off; off >>= 1) {
        a  += __shfl_xor(a,  off);
        b2 += __shfl_xor(b2, off);
    }
    __shared__ float red[8];
    __shared__ float red2[4];
    int wave = threadIdx.x >> 6;
    if ((threadIdx.x & 63) == 0) { red[wave] = a; red[4 + wave] = b2; }
    __syncthreads();
    float sum   = red[0] + red[1] + red[2] + red[3];
    float sumsq = red[4] + red[5] + red[6] + red[7];
    float mu  = sum * (1.0f / D_);
    float var = sumsq * (1.0f / D_) - mu * mu;
    float rs  = rsqrtf(var + 1e-6f);
    float yv  = (v - mu) * rs * s[d] + bb[d];
    float p   = yv * Wout[d];
    #pragma unroll
    for (int off = 32; off; off >>= 1) p += __shfl_xor(p, off);
    if ((threadIdx.x & 63) == 0) red2[wave] = p;
    __syncthreads();
    if (threadIdx.x == 0)
        out[t] = red2[0] + red2[1] + red2[2] + red2[3] + bout[0];
}

// =====================================================================
// launch
// =====================================================================
extern "C" void kernel_launch(void* const* d_in, const int* in_sizes, int n_in,
                              void* d_out, int out_size, void* d_ws, size_t ws_size,
                              hipStream_t stream) {
    const int*   x       = (const int*)  d_in[0];
    const float* Win     = (const float*)d_in[1];
    const float* b_in    = (const float*)d_in[2];
    const float* lnA_s   = (const float*)d_in[3];
    const float* lnA_b   = (const float*)d_in[4];
    const float* Wq      = (const float*)d_in[5];
    const float* bq      = (const float*)d_in[6];
    const float* Wk      = (const float*)d_in[7];
    const float* bk      = (const float*)d_in[8];
    const float* Wv      = (const float*)d_in[9];
    const float* bv      = (const float*)d_in[10];
    const float* Wo      = (const float*)d_in[11];
    const float* bo      = (const float*)d_in[12];
    const float* lnB_s   = (const float*)d_in[13];
    const float* lnB_b   = (const float*)d_in[14];
    const float* W1      = (const float*)d_in[15];
    const float* b1      = (const float*)d_in[16];
    const float* W2      = (const float*)d_in[17];
    const float* b2      = (const float*)d_in[18];
    const float* rel_emb = (const float*)d_in[19];
    const float* lnF_s   = (const float*)d_in[20];
    const float* lnF_b   = (const float*)d_in[21];
    const float* Wout    = (const float*)d_in[22];
    const float* bout    = (const float*)d_in[23];
    float* out = (float*)d_out;

    // workspace layout (floats): h | y | q | k | v | extra
    // t-buffer (NT_*MLP_) overlaps [q|k|v|extra] (q,k,v dead after attention)
    float* ws   = (float*)d_ws;
    float* h    = ws;
    float* y    = h + (size_t)NT_ * D_;
    float* q    = y + (size_t)NT_ * D_;
    float* k    = q + (size_t)NT_ * D_;
    float* v    = k + (size_t)NT_ * D_;
    float* att  = y;                       // reuse y after QKV projections
    float* tbuf = q;                       // spans q,k,v,extra = NT_*1024 floats

    dim3 blk(256);
    embed_kernel<<<NT_, blk, 0, stream>>>(x, Win, b_in, h);

    for (int layer = 0; layer < NL_; ++layer) {
        const float* wq = Wq + (size_t)layer * D_ * D_;
        const float* wk = Wk + (size_t)layer * D_ * D_;
        const float* wv = Wv + (size_t)layer * D_ * D_;
        const float* wo = Wo + (size_t)layer * D_ * D_;
        const float* w1 = W1 + (size_t)layer * D_ * MLP_;
        const float* w2 = W2 + (size_t)layer * MLP_ * D_;

        ln_kernel<<<NT_, blk, 0, stream>>>(h, lnA_s + layer * D_, lnA_b + layer * D_, y);

        dim3 g256(D_ / 64, NT_ / 64);     // (4,144)
        gemm_kernel<false, false><<<g256, blk, 0, stream>>>(y, wq, bq + layer * D_, nullptr, q, NT_, D_, D_);
        gemm_kernel<false, false><<<g256, blk, 0, stream>>>(y, wk, bk + layer * D_, nullptr, k, NT_, D_, D_);
        gemm_kernel<false, false><<<g256, blk, 0, stream>>>(y, wv, bv + layer * D_, nullptr, v, NT_, D_, D_);

        attn_kernel<<<NT_, blk, 0, stream>>>(q, k, v, rel_emb, att);

        // h = h + att @ Wo + bo
        gemm_kernel<false, true><<<g256, blk, 0, stream>>>(att, wo, bo + layer * D_, h, h, NT_, D_, D_);

        ln_kernel<<<NT_, blk, 0, stream>>>(h, lnB_s + layer * D_, lnB_b + layer * D_, y);

        dim3 g1024(MLP_ / 64, NT_ / 64);  // (16,144)
        gemm_kernel<true, false><<<g1024, blk, 0, stream>>>(y, w1, b1 + layer * MLP_, nullptr, tbuf, NT_, MLP_, D_);
        // h = h + gelu(...) @ W2 + b2
        gemm_kernel<false, true><<<g256, blk, 0, stream>>>(tbuf, w2, b2 + layer * D_, h, h, NT_, D_, MLP_);
    }

    final_kernel<<<NT_, blk, 0, stream>>>(h, lnF_s, lnF_b, Wout, bout, out);
}

// Round 4
// 760.322 us; speedup vs baseline: 2.6648x; 2.6648x over previous
//
#include <hip/hip_runtime.h>
#include <hip/hip_bf16.h>
#include <math.h>

// ---- static problem dims ----
#define NT_   9216          // B*L tokens
#define D_    256
#define NH_   8
#define HD_   32
#define L_    2304
#define HH_   48
#define WW_   48
#define MLP_  1024
#define NL_   4

typedef __attribute__((ext_vector_type(8))) short bf16x8;
typedef __attribute__((ext_vector_type(4))) float f32x4;

// =====================================================================
// helpers
// =====================================================================
__device__ __forceinline__ float gelu_tanh(float x) {
    const float c0 = 0.7978845608028654f;   // sqrt(2/pi)
    const float c1 = 0.044715f;
    float u = c0 * (x + c1 * x * x * x);
    return 0.5f * x * (1.0f + tanhf(u));
}

__device__ __forceinline__ void gload16(const void* gsrc, void* ldst) {
    __builtin_amdgcn_global_load_lds(
        (const __attribute__((address_space(1))) void*)gsrc,
        (__attribute__((address_space(3))) void*)ldst, 16, 0, 0);
}

// =====================================================================
// prep: fp32 [K][N] -> bf16 [N][K] transpose+convert, batched over layers
// block 32x8, one 32x32 tile per block. out base may include a column
// offset (QKV packing); out index = n*K + k.
// =====================================================================
__global__ void tcvt_kernel(const float* __restrict__ in, __hip_bfloat16* __restrict__ out,
                            int K, int N, int inLayerStride, int outLayerStride) {
    __shared__ float t[32][33];
    int l = blockIdx.z;
    int n0 = blockIdx.x * 32, k0 = blockIdx.y * 32;
    int tx = threadIdx.x, ty = threadIdx.y;
    const float* src = in + (size_t)l * inLayerStride;
    #pragma unroll
    for (int r = 0; r < 32; r += 8)
        t[ty + r][tx] = src[(size_t)(k0 + ty + r) * N + n0 + tx];
    __syncthreads();
    __hip_bfloat16* dst = out + (size_t)l * outLayerStride;
    #pragma unroll
    for (int r = 0; r < 32; r += 8)
        dst[(size_t)(n0 + ty + r) * K + k0 + tx] = __float2bfloat16(t[tx][ty + r]);
}

// concat bq|bk|bv -> bqkv[NL][768]
__global__ void bcat_kernel(const float* __restrict__ bq, const float* __restrict__ bk,
                            const float* __restrict__ bv, float* __restrict__ bqkv) {
    int l = blockIdx.x, n = threadIdx.x;
    float v = (n < 256) ? bq[l * 256 + n] : (n < 512 ? bk[l * 256 + n - 256] : bv[l * 256 + n - 512]);
    bqkv[l * 768 + n] = v;
}

// =====================================================================
// embed: h[t][d] = x*Win[0][d] + yn*Win[1][d] + xn*Win[2][d] + b_in[d]
// =====================================================================
__global__ void embed_kernel(const int* __restrict__ x, const float* __restrict__ Win,
                             const float* __restrict__ b_in, float* __restrict__ h) {
    int t = blockIdx.x, d = threadIdx.x;
    int l = t % L_;
    int yy = l / WW_, xx = l % WW_;
    float xv = (float)x[t];
    float yn = yy * (1.0f / 47.0f);
    float xn = xx * (1.0f / 47.0f);
    h[t * D_ + d] = xv * Win[d] + yn * Win[D_ + d] + xn * Win[2 * D_ + d] + b_in[d];
}

// =====================================================================
// LayerNorm -> bf16 output (GEMM A operand)
// =====================================================================
__global__ void ln_kernel(const float* __restrict__ h, const float* __restrict__ s,
                          const float* __restrict__ bb, __hip_bfloat16* __restrict__ y) {
    int t = blockIdx.x, d = threadIdx.x;
    float v = h[t * D_ + d];
    float a = v, b2 = v * v;
    #pragma unroll
    for (int off = 32; off; off >>= 1) {
        a  += __shfl_xor(a,  off);
        b2 += __shfl_xor(b2, off);
    }
    __shared__ float red[8];
    int wave = threadIdx.x >> 6;
    if ((threadIdx.x & 63) == 0) { red[wave] = a; red[4 + wave] = b2; }
    __syncthreads();
    float sum   = red[0] + red[1] + red[2] + red[3];
    float sumsq = red[4] + red[5] + red[6] + red[7];
    float mu  = sum * (1.0f / D_);
    float var = sumsq * (1.0f / D_) - mu * mu;
    float rs  = rsqrtf(var + 1e-6f);
    y[t * D_ + d] = __float2bfloat16((v - mu) * rs * s[d] + bb[d]);
}

// =====================================================================
// local attention (25-neighbor torus window). qkv fp32 [NT][768].
// out att bf16 [NT][256].
// =====================================================================
__global__ void attn_kernel(const float* __restrict__ qkv, const float* __restrict__ rel_emb,
                            __hip_bfloat16* __restrict__ att) {
    int t = blockIdx.x;
    int hh = threadIdx.x >> 5;
    int e  = threadIdx.x & 31;
    int b  = t / L_;
    int l  = t - b * L_;
    int yy = l / WW_, xx = l - yy * WW_;

    float qv = qkv[(size_t)t * 768 + hh * HD_ + e];
    const float scale = 0.17677669529663687f;

    float scores[25];
    int   nidx[25];
    #pragma unroll
    for (int oy = -2; oy <= 2; ++oy) {
        #pragma unroll
        for (int ox = -2; ox <= 2; ++ox) {
            int j = (oy + 2) * 5 + (ox + 2);
            int ny = yy + oy; ny += (ny < 0) ? HH_ : 0; ny -= (ny >= HH_) ? HH_ : 0;
            int nx = xx + ox; nx += (nx < 0) ? WW_ : 0; nx -= (nx >= WW_) ? WW_ : 0;
            int nt = b * L_ + ny * WW_ + nx;
            nidx[j] = nt;
            float kv = qkv[(size_t)nt * 768 + 256 + hh * HD_ + e];
            float dot = qv * kv;
            #pragma unroll
            for (int off = 16; off; off >>= 1) dot += __shfl_xor(dot, off, 32);
            float bias = rel_emb[hh * 225 + (7 - oy) * 15 + (7 - ox)];
            scores[j] = dot * scale + bias;
        }
    }
    float m = scores[0];
    #pragma unroll
    for (int j = 1; j < 25; ++j) m = fmaxf(m, scores[j]);
    float sum = 0.0f;
    #pragma unroll
    for (int j = 0; j < 25; ++j) { scores[j] = expf(scores[j] - m); sum += scores[j]; }
    float inv = 1.0f / sum;
    float acc = 0.0f;
    #pragma unroll
    for (int j = 0; j < 25; ++j) acc += scores[j] * qkv[(size_t)nidx[j] * 768 + 512 + hh * HD_ + e];
    att[t * D_ + hh * HD_ + e] = __float2bfloat16(acc * inv);
}

// =====================================================================
// bf16 MFMA GEMM (m97 structure): C[M,N] = A[M,K] @ BT[N,K]^T + bias
// BM=BN=128, BK=32, 256 threads = 4 waves (2x2), wave tile 64x64 =
// 4x4 fragments of 16x16x32. global_load_lds(16B) staging, k-contiguous
// LDS rows, ds_read_b128 fragment loads, fp32 accumulate.
// EPI: 0 = bias -> fp32; 1 = bias+res -> fp32; 2 = bias+gelu -> bf16
// =====================================================================
template<int EPI>
__global__ __launch_bounds__(256, 2)
void mgemm(const __hip_bfloat16* __restrict__ A, const __hip_bfloat16* __restrict__ BT,
           const float* __restrict__ bias, const float* res,
           float* Cf, __hip_bfloat16* Cb, int M, int N, int K) {
    __shared__ __hip_bfloat16 As[128 * 32];
    __shared__ __hip_bfloat16 Bs[128 * 32];
    const int bm = blockIdx.y * 128, bn = blockIdx.x * 128;
    const int tid = threadIdx.x, lane = tid & 63, wv = tid >> 6;
    const int wm = (wv >> 1) * 64, wn = (wv & 1) * 64;

    // staging addresses: instr i covers LDS rows 16i..16i+15; lane l ->
    // row 16i + (l>>2), k-chunk 8*(l&3). Wave w issues instrs {w, w+4}.
    const __hip_bfloat16* aSrc = A + (size_t)(bm + 16 * wv + (lane >> 2)) * K + (lane & 3) * 8;
    const __hip_bfloat16* bSrc = BT + (size_t)(bn + 16 * wv + (lane >> 2)) * K + (lane & 3) * 8;
    __hip_bfloat16* aDst0 = As + wv * 512;
    __hip_bfloat16* aDst1 = As + (wv + 4) * 512;
    __hip_bfloat16* bDst0 = Bs + wv * 512;
    __hip_bfloat16* bDst1 = Bs + (wv + 4) * 512;
    const size_t rowJump = (size_t)64 * K;

    f32x4 acc[4][4];
    #pragma unroll
    for (int i = 0; i < 4; ++i)
        #pragma unroll
        for (int j = 0; j < 4; ++j)
            acc[i][j] = (f32x4){0.f, 0.f, 0.f, 0.f};

    const int rsel = (lane & 15);      // fragment row/col within 16
    const int ko   = (lane >> 4) * 8;  // k-offset within 32

    for (int k0 = 0; k0 < K; k0 += 32) {
        gload16(aSrc,            aDst0);
        gload16(aSrc + rowJump,  aDst1);
        gload16(bSrc,            bDst0);
        gload16(bSrc + rowJump,  bDst1);
        __syncthreads();   // drains vmcnt -> staged data visible

        bf16x8 af[4], bfr[4];
        #pragma unroll
        for (int f = 0; f < 4; ++f) {
            af[f]  = *(const bf16x8*)(As + (wm + f * 16 + rsel) * 32 + ko);
            bfr[f] = *(const bf16x8*)(Bs + (wn + f * 16 + rsel) * 32 + ko);
        }
        #pragma unroll
        for (int i = 0; i < 4; ++i)
            #pragma unroll
            for (int j = 0; j < 4; ++j)
                acc[i][j] = __builtin_amdgcn_mfma_f32_16x16x32_bf16(af[i], bfr[j], acc[i][j], 0, 0, 0);
        __syncthreads();
        aSrc += 32; bSrc += 32;
    }

    // epilogue: D row = wm + i*16 + (lane>>4)*4 + r, col = wn + j*16 + (lane&15)
    #pragma unroll
    for (int i = 0; i < 4; ++i) {
        #pragma unroll
        for (int r = 0; r < 4; ++r) {
            int rr = bm + wm + i * 16 + (lane >> 4) * 4 + r;
            #pragma unroll
            for (int j = 0; j < 4; ++j) {
                int cc = bn + wn + j * 16 + rsel;
                float v = acc[i][j][r] + bias[cc];
                if (EPI == 2) {
                    Cb[(size_t)rr * N + cc] = __float2bfloat16(gelu_tanh(v));
                } else {
                    if (EPI == 1) v += res[(size_t)rr * N + cc];
                    Cf[(size_t)rr * N + cc] = v;
                }
            }
        }
    }
}

// =====================================================================
// final: fused LN(lnF) + dot with Wout + bout -> logits[t]
// =====================================================================
__global__ void final_kernel(const float* __restrict__ h, const float* __restrict__ s,
                             const float* __restrict__ bb, const float* __restrict__ Wout,
                             const float* __restrict__ bout, float* __restrict__ out) {
    int t = blockIdx.x, d = threadIdx.x;
    float v = h[t * D_ + d];
    float a = v, b2 = v * v;
    #pragma unroll
    for (int off = 32; off; off >>= 1) {
        a  += __shfl_xor(a,  off);
        b2 += __shfl_xor(b2, off);
    }
    __shared__ float red[8];
    __shared__ float red2[4];
    int wave = threadIdx.x >> 6;
    if ((threadIdx.x & 63) == 0) { red[wave] = a; red[4 + wave] = b2; }
    __syncthreads();
    float sum   = red[0] + red[1] + red[2] + red[3];
    float sumsq = red[4] + red[5] + red[6] + red[7];
    float mu  = sum * (1.0f / D_);
    float var = sumsq * (1.0f / D_) - mu * mu;
    float rs  = rsqrtf(var + 1e-6f);
    float yv  = (v - mu) * rs * s[d] + bb[d];
    float p   = yv * Wout[d];
    #pragma unroll
    for (int off = 32; off; off >>= 1) p += __shfl_xor(p, off);
    if ((threadIdx.x & 63) == 0) red2[wave] = p;
    __syncthreads();
    if (threadIdx.x == 0)
        out[t] = red2[0] + red2[1] + red2[2] + red2[3] + bout[0];
}

// =====================================================================
// launch
// =====================================================================
extern "C" void kernel_launch(void* const* d_in, const int* in_sizes, int n_in,
                              void* d_out, int out_size, void* d_ws, size_t ws_size,
                              hipStream_t stream) {
    const int*   x       = (const int*)  d_in[0];
    const float* Win     = (const float*)d_in[1];
    const float* b_in    = (const float*)d_in[2];
    const float* lnA_s   = (const float*)d_in[3];
    const float* lnA_b   = (const float*)d_in[4];
    const float* Wq      = (const float*)d_in[5];
    const float* bq      = (const float*)d_in[6];
    const float* Wk      = (const float*)d_in[7];
    const float* bk      = (const float*)d_in[8];
    const float* Wv      = (const float*)d_in[9];
    const float* bv      = (const float*)d_in[10];
    const float* Wo      = (const float*)d_in[11];
    const float* bo      = (const float*)d_in[12];
    const float* lnB_s   = (const float*)d_in[13];
    const float* lnB_b   = (const float*)d_in[14];
    const float* W1      = (const float*)d_in[15];
    const float* b1      = (const float*)d_in[16];
    const float* W2      = (const float*)d_in[17];
    const float* b2      = (const float*)d_in[18];
    const float* rel_emb = (const float*)d_in[19];
    const float* lnF_s   = (const float*)d_in[20];
    const float* lnF_b   = (const float*)d_in[21];
    const float* Wout    = (const float*)d_in[22];
    const float* bout    = (const float*)d_in[23];
    float* out = (float*)d_out;

    // ---- workspace layout (float offsets) ----
    float* ws = (float*)d_ws;
    float*          h      = ws;                                   // 2359296 f
    __hip_bfloat16* y      = (__hip_bfloat16*)(ws + 2359296);      // 1179648 f
    float*          qkv    = ws + 3538944;                         // 7077888 f
    __hip_bfloat16* att    = (__hip_bfloat16*)(ws + 10616832);     // 1179648 f
    __hip_bfloat16* tbuf   = (__hip_bfloat16*)qkv;                 // overlap (qkv dead after attn)
    __hip_bfloat16* WqkvT  = (__hip_bfloat16*)(ws + 11796480);     // 4*768*256  bf16
    __hip_bfloat16* WoT    = WqkvT + 4 * 768 * 256;                // 4*256*256
    __hip_bfloat16* W1T    = WoT   + 4 * 256 * 256;                // 4*1024*256
    __hip_bfloat16* W2T    = W1T   + 4 * 1024 * 256;               // 4*256*1024
    float*          bqkv   = (float*)(W2T + 4 * 256 * 1024);       // 4*768 f

    dim3 blk(256);
    dim3 tb(32, 8);

    // ---- weight prep: transpose + bf16 convert ----
    tcvt_kernel<<<dim3(8, 8, 4),  tb, 0, stream>>>(Wq, WqkvT,              256, 256,  65536, 196608);
    tcvt_kernel<<<dim3(8, 8, 4),  tb, 0, stream>>>(Wk, WqkvT + 256 * 256,  256, 256,  65536, 196608);
    tcvt_kernel<<<dim3(8, 8, 4),  tb, 0, stream>>>(Wv, WqkvT + 512 * 256,  256, 256,  65536, 196608);
    tcvt_kernel<<<dim3(8, 8, 4),  tb, 0, stream>>>(Wo, WoT,                256, 256,  65536, 65536);
    tcvt_kernel<<<dim3(32, 8, 4), tb, 0, stream>>>(W1, W1T,                256, 1024, 262144, 262144);
    tcvt_kernel<<<dim3(8, 32, 4), tb, 0, stream>>>(W2, W2T,                1024, 256, 262144, 262144);
    bcat_kernel<<<4, 768, 0, stream>>>(bq, bk, bv, bqkv);

    embed_kernel<<<NT_, blk, 0, stream>>>(x, Win, b_in, h);

    for (int l = 0; l < NL_; ++l) {
        const __hip_bfloat16* wqkv = WqkvT + (size_t)l * 768 * 256;
        const __hip_bfloat16* wo   = WoT   + (size_t)l * 256 * 256;
        const __hip_bfloat16* w1   = W1T   + (size_t)l * 1024 * 256;
        const __hip_bfloat16* w2   = W2T   + (size_t)l * 256 * 1024;

        ln_kernel<<<NT_, blk, 0, stream>>>(h, lnA_s + l * D_, lnA_b + l * D_, y);

        mgemm<0><<<dim3(6, 72), blk, 0, stream>>>(y, wqkv, bqkv + l * 768, nullptr,
                                                  qkv, nullptr, NT_, 768, 256);
        attn_kernel<<<NT_, blk, 0, stream>>>(qkv, rel_emb, att);
        mgemm<1><<<dim3(2, 72), blk, 0, stream>>>(att, wo, bo + l * D_, h,
                                                  h, nullptr, NT_, 256, 256);

        ln_kernel<<<NT_, blk, 0, stream>>>(h, lnB_s + l * D_, lnB_b + l * D_, y);

        mgemm<2><<<dim3(8, 72), blk, 0, stream>>>(y, w1, b1 + l * MLP_, nullptr,
                                                  nullptr, tbuf, NT_, 1024, 256);
        mgemm<1><<<dim3(2, 72), blk, 0, stream>>>(tbuf, w2, b2 + l * D_, h,
                                                  h, nullptr, NT_, 256, 1024);
    }

    final_kernel<<<NT_, blk, 0, stream>>>(h, lnF_s, lnF_b, Wout, bout, out);
}

// Round 5
// 747.894 us; speedup vs baseline: 2.7091x; 1.0166x over previous
//
#include <hip/hip_runtime.h>
#include <hip/hip_bf16.h>
#include <math.h>

// ---- static problem dims ----
#define NT_   9216          // B*L tokens
#define D_    256
#define NH_   8
#define HD_   32
#define L_    2304
#define HH_   48
#define WW_   48
#define MLP_  1024
#define NL_   4

typedef __attribute__((ext_vector_type(8))) short bf16x8;
typedef __attribute__((ext_vector_type(4))) float f32x4;

// =====================================================================
// helpers
// =====================================================================
__device__ __forceinline__ float gelu_tanh(float x) {
    const float c0 = 0.7978845608028654f;   // sqrt(2/pi)
    const float c1 = 0.044715f;
    float u = c0 * (x + c1 * x * x * x);
    return 0.5f * x * (1.0f + tanhf(u));
}

__device__ __forceinline__ void gload16(const void* gsrc, void* ldst) {
    __builtin_amdgcn_global_load_lds(
        (const __attribute__((address_space(1))) void*)gsrc,
        (__attribute__((address_space(3))) void*)ldst, 16, 0, 0);
}

__device__ __forceinline__ unsigned short f2bf(float f) {
    __hip_bfloat16 h = __float2bfloat16(f);
    return *(unsigned short*)&h;
}

// =====================================================================
// prep: fp32 [K][N] -> bf16 [N][K] transpose+convert, batched over layers
// =====================================================================
__global__ void tcvt_kernel(const float* __restrict__ in, __hip_bfloat16* __restrict__ out,
                            int K, int N, int inLayerStride, int outLayerStride) {
    __shared__ float t[32][33];
    int l = blockIdx.z;
    int n0 = blockIdx.x * 32, k0 = blockIdx.y * 32;
    int tx = threadIdx.x, ty = threadIdx.y;
    const float* src = in + (size_t)l * inLayerStride;
    #pragma unroll
    for (int r = 0; r < 32; r += 8)
        t[ty + r][tx] = src[(size_t)(k0 + ty + r) * N + n0 + tx];
    __syncthreads();
    __hip_bfloat16* dst = out + (size_t)l * outLayerStride;
    #pragma unroll
    for (int r = 0; r < 32; r += 8)
        dst[(size_t)(n0 + ty + r) * K + k0 + tx] = __float2bfloat16(t[tx][ty + r]);
}

// concat bq|bk|bv -> bqkv[NL][768]
__global__ void bcat_kernel(const float* __restrict__ bq, const float* __restrict__ bk,
                            const float* __restrict__ bv, float* __restrict__ bqkv) {
    int l = blockIdx.x, n = threadIdx.x;
    float v = (n < 256) ? bq[l * 256 + n] : (n < 512 ? bk[l * 256 + n - 256] : bv[l * 256 + n - 512]);
    bqkv[l * 768 + n] = v;
}

// =====================================================================
// embed
// =====================================================================
__global__ void embed_kernel(const int* __restrict__ x, const float* __restrict__ Win,
                             const float* __restrict__ b_in, float* __restrict__ h) {
    int t = blockIdx.x, d = threadIdx.x;
    int l = t % L_;
    int yy = l / WW_, xx = l % WW_;
    float xv = (float)x[t];
    float yn = yy * (1.0f / 47.0f);
    float xn = xx * (1.0f / 47.0f);
    h[t * D_ + d] = xv * Win[d] + yn * Win[D_ + d] + xn * Win[2 * D_ + d] + b_in[d];
}

// =====================================================================
// LayerNorm -> bf16. One wave per token, float4 per lane, 8B bf16 stores.
// grid NT_/4 blocks x 256 threads (4 waves).
// =====================================================================
__global__ void ln_kernel(const float* __restrict__ h, const float* __restrict__ s,
                          const float* __restrict__ bb, __hip_bfloat16* __restrict__ y) {
    int wid = threadIdx.x >> 6, lane = threadIdx.x & 63;
    int t = (blockIdx.x << 2) + wid;
    float4 v = *(const float4*)(h + (size_t)t * D_ + lane * 4);
    float sum = v.x + v.y + v.z + v.w;
    float sq  = v.x * v.x + v.y * v.y + v.z * v.z + v.w * v.w;
    #pragma unroll
    for (int off = 32; off; off >>= 1) {
        sum += __shfl_xor(sum, off);
        sq  += __shfl_xor(sq,  off);
    }
    float mu  = sum * (1.0f / D_);
    float var = sq * (1.0f / D_) - mu * mu;
    float rs  = rsqrtf(var + 1e-6f);
    float4 s4 = *(const float4*)(s  + lane * 4);
    float4 b4 = *(const float4*)(bb + lane * 4);
    ushort4 o;
    o.x = f2bf((v.x - mu) * rs * s4.x + b4.x);
    o.y = f2bf((v.y - mu) * rs * s4.y + b4.y);
    o.z = f2bf((v.z - mu) * rs * s4.z + b4.z);
    o.w = f2bf((v.w - mu) * rs * s4.w + b4.w);
    *(ushort4*)(y + (size_t)t * D_ + lane * 4) = o;
}

// =====================================================================
// local attention, lane-per-neighbor. 25-neighbor torus window.
// block = 1 token, 256 threads = 8 heads x 32 lanes.
// Dot phase: lane j in [0,25) serially dots q . k[neighbor j] (32 FMA).
// Softmax: 5-shfl max/sum over the 32-lane group; exp underflows to 0
// on idle lanes (score -1e30), identical math to reference.
// PV phase: lane = output dim; p_j / row_j broadcast by shfl.
// =====================================================================
__global__ void attn_kernel(const float* __restrict__ qkv, const float* __restrict__ rel_emb,
                            __hip_bfloat16* __restrict__ att) {
    const int t  = blockIdx.x;
    const int hh = threadIdx.x >> 5;
    const int j  = threadIdx.x & 31;     // neighbor id (dot) / dim id (PV)
    const int b  = t / L_;
    const int l  = t - b * L_;
    const int yy = l / WW_, xx = l - yy * WW_;

    // per-lane neighbor row index
    int oy2 = j / 5, ox2 = j - oy2 * 5;
    bool valid = (j < 25);
    int ny = yy + oy2 - 2; ny += (ny < 0) ? HH_ : 0; ny -= (ny >= HH_) ? HH_ : 0;
    int nx = xx + ox2 - 2; nx += (nx < 0) ? WW_ : 0; nx -= (nx >= WW_) ? WW_ : 0;
    int rowidx = valid ? (b * L_ + ny * WW_ + nx) : t;   // clamp idle lanes

    // q into registers (broadcast loads, 32 floats)
    const float* qp = qkv + (size_t)t * 768 + hh * HD_;
    float4 q4[8];
    #pragma unroll
    for (int d = 0; d < 8; ++d) q4[d] = ((const float4*)qp)[d];

    // serial dot: lane j computes q . k[rowidx]
    const float* kp = qkv + (size_t)rowidx * 768 + 256 + hh * HD_;
    float dot = 0.f;
    #pragma unroll
    for (int d = 0; d < 8; ++d) {
        float4 k4 = ((const float4*)kp)[d];
        dot += q4[d].x * k4.x + q4[d].y * k4.y + q4[d].z * k4.z + q4[d].w * k4.w;
    }
    // bias bucket: (7-oy)*15+(7-ox) with oy=oy2-2, ox=ox2-2
    float bias = rel_emb[hh * 225 + (9 - oy2) * 15 + (9 - ox2)];
    float s = valid ? (dot * 0.17677669529663687f + bias) : -1e30f;

    // softmax over the 32-lane group (25 live)
    float m = s;
    #pragma unroll
    for (int off = 16; off; off >>= 1) m = fmaxf(m, __shfl_xor(m, off, 32));
    float p = __expf(s - m);            // idle lanes -> 0
    float sum = p;
    #pragma unroll
    for (int off = 16; off; off >>= 1) sum += __shfl_xor(sum, off, 32);
    float inv = 1.0f / sum;

    // PV: lane j owns output dim
    const float* vbase = qkv + 512 + hh * HD_ + j;
    float acc = 0.f;
    #pragma unroll
    for (int n = 0; n < 25; ++n) {
        float pn = __shfl(p, n, 32);
        int   rn = __shfl(rowidx, n, 32);
        acc += pn * vbase[(size_t)rn * 768];
    }
    att[t * D_ + hh * HD_ + j] = __float2bfloat16(acc * inv);
}

// =====================================================================
// bf16 MFMA GEMM (m97 structure): C[M,N] = A[M,K] @ BT[N,K]^T + bias
// EPI: 0 = bias -> fp32; 1 = bias+res -> fp32; 2 = bias+gelu -> bf16
// =====================================================================
template<int EPI>
__global__ __launch_bounds__(256, 2)
void mgemm(const __hip_bfloat16* __restrict__ A, const __hip_bfloat16* __restrict__ BT,
           const float* __restrict__ bias, const float* res,
           float* Cf, __hip_bfloat16* Cb, int M, int N, int K) {
    __shared__ __hip_bfloat16 As[128 * 32];
    __shared__ __hip_bfloat16 Bs[128 * 32];
    const int bm = blockIdx.y * 128, bn = blockIdx.x * 128;
    const int tid = threadIdx.x, lane = tid & 63, wv = tid >> 6;
    const int wm = (wv >> 1) * 64, wn = (wv & 1) * 64;

    const __hip_bfloat16* aSrc = A + (size_t)(bm + 16 * wv + (lane >> 2)) * K + (lane & 3) * 8;
    const __hip_bfloat16* bSrc = BT + (size_t)(bn + 16 * wv + (lane >> 2)) * K + (lane & 3) * 8;
    __hip_bfloat16* aDst0 = As + wv * 512;
    __hip_bfloat16* aDst1 = As + (wv + 4) * 512;
    __hip_bfloat16* bDst0 = Bs + wv * 512;
    __hip_bfloat16* bDst1 = Bs + (wv + 4) * 512;
    const size_t rowJump = (size_t)64 * K;

    f32x4 acc[4][4];
    #pragma unroll
    for (int i = 0; i < 4; ++i)
        #pragma unroll
        for (int j = 0; j < 4; ++j)
            acc[i][j] = (f32x4){0.f, 0.f, 0.f, 0.f};

    const int rsel = (lane & 15);
    const int ko   = (lane >> 4) * 8;

    for (int k0 = 0; k0 < K; k0 += 32) {
        gload16(aSrc,            aDst0);
        gload16(aSrc + rowJump,  aDst1);
        gload16(bSrc,            bDst0);
        gload16(bSrc + rowJump,  bDst1);
        __syncthreads();

        bf16x8 af[4], bfr[4];
        #pragma unroll
        for (int f = 0; f < 4; ++f) {
            af[f]  = *(const bf16x8*)(As + (wm + f * 16 + rsel) * 32 + ko);
            bfr[f] = *(const bf16x8*)(Bs + (wn + f * 16 + rsel) * 32 + ko);
        }
        #pragma unroll
        for (int i = 0; i < 4; ++i)
            #pragma unroll
            for (int j = 0; j < 4; ++j)
                acc[i][j] = __builtin_amdgcn_mfma_f32_16x16x32_bf16(af[i], bfr[j], acc[i][j], 0, 0, 0);
        __syncthreads();
        aSrc += 32; bSrc += 32;
    }

    #pragma unroll
    for (int i = 0; i < 4; ++i) {
        #pragma unroll
        for (int r = 0; r < 4; ++r) {
            int rr = bm + wm + i * 16 + (lane >> 4) * 4 + r;
            #pragma unroll
            for (int j = 0; j < 4; ++j) {
                int cc = bn + wn + j * 16 + rsel;
                float v = acc[i][j][r] + bias[cc];
                if (EPI == 2) {
                    Cb[(size_t)rr * N + cc] = __float2bfloat16(gelu_tanh(v));
                } else {
                    if (EPI == 1) v += res[(size_t)rr * N + cc];
                    Cf[(size_t)rr * N + cc] = v;
                }
            }
        }
    }
}

// =====================================================================
// final: fused LN(lnF) + dot with Wout + bout -> logits[t]
// =====================================================================
__global__ void final_kernel(const float* __restrict__ h, const float* __restrict__ s,
                             const float* __restrict__ bb, const float* __restrict__ Wout,
                             const float* __restrict__ bout, float* __restrict__ out) {
    int t = blockIdx.x, d = threadIdx.x;
    float v = h[t * D_ + d];
    float a = v, b2 = v * v;
    #pragma unroll
    for (int off = 32; off; off >>= 1) {
        a  += __shfl_xor(a,  off);
        b2 += __shfl_xor(b2, off);
    }
    __shared__ float red[8];
    __shared__ float red2[4];
    int wave = threadIdx.x >> 6;
    if ((threadIdx.x & 63) == 0) { red[wave] = a; red[4 + wave] = b2; }
    __syncthreads();
    float sum   = red[0] + red[1] + red[2] + red[3];
    float sumsq = red[4] + red[5] + red[6] + red[7];
    float mu  = sum * (1.0f / D_);
    float var = sumsq * (1.0f / D_) - mu * mu;
    float rs  = rsqrtf(var + 1e-6f);
    float yv  = (v - mu) * rs * s[d] + bb[d];
    float p   = yv * Wout[d];
    #pragma unroll
    for (int off = 32; off; off >>= 1) p += __shfl_xor(p, off);
    if ((threadIdx.x & 63) == 0) red2[wave] = p;
    __syncthreads();
    if (threadIdx.x == 0)
        out[t] = red2[0] + red2[1] + red2[2] + red2[3] + bout[0];
}

// =====================================================================
// launch
// =====================================================================
extern "C" void kernel_launch(void* const* d_in, const int* in_sizes, int n_in,
                              void* d_out, int out_size, void* d_ws, size_t ws_size,
                              hipStream_t stream) {
    const int*   x       = (const int*)  d_in[0];
    const float* Win     = (const float*)d_in[1];
    const float* b_in    = (const float*)d_in[2];
    const float* lnA_s   = (const float*)d_in[3];
    const float* lnA_b   = (const float*)d_in[4];
    const float* Wq      = (const float*)d_in[5];
    const float* bq      = (const float*)d_in[6];
    const float* Wk      = (const float*)d_in[7];
    const float* bk      = (const float*)d_in[8];
    const float* Wv      = (const float*)d_in[9];
    const float* bv      = (const float*)d_in[10];
    const float* Wo      = (const float*)d_in[11];
    const float* bo      = (const float*)d_in[12];
    const float* lnB_s   = (const float*)d_in[13];
    const float* lnB_b   = (const float*)d_in[14];
    const float* W1      = (const float*)d_in[15];
    const float* b1      = (const float*)d_in[16];
    const float* W2      = (const float*)d_in[17];
    const float* b2      = (const float*)d_in[18];
    const float* rel_emb = (const float*)d_in[19];
    const float* lnF_s   = (const float*)d_in[20];
    const float* lnF_b   = (const float*)d_in[21];
    const float* Wout    = (const float*)d_in[22];
    const float* bout    = (const float*)d_in[23];
    float* out = (float*)d_out;

    // ---- workspace layout (float offsets) ----
    float* ws = (float*)d_ws;
    float*          h      = ws;                                   // 2359296 f
    __hip_bfloat16* y      = (__hip_bfloat16*)(ws + 2359296);      // 1179648 f
    float*          qkv    = ws + 3538944;                         // 7077888 f
    __hip_bfloat16* att    = (__hip_bfloat16*)(ws + 10616832);     // 1179648 f
    __hip_bfloat16* tbuf   = (__hip_bfloat16*)qkv;                 // overlap (qkv dead after attn)
    __hip_bfloat16* WqkvT  = (__hip_bfloat16*)(ws + 11796480);     // 4*768*256  bf16
    __hip_bfloat16* WoT    = WqkvT + 4 * 768 * 256;                // 4*256*256
    __hip_bfloat16* W1T    = WoT   + 4 * 256 * 256;                // 4*1024*256
    __hip_bfloat16* W2T    = W1T   + 4 * 1024 * 256;               // 4*256*1024
    float*          bqkv   = (float*)(W2T + 4 * 256 * 1024);       // 4*768 f

    dim3 blk(256);
    dim3 tb(32, 8);

    // ---- weight prep: transpose + bf16 convert ----
    tcvt_kernel<<<dim3(8, 8, 4),  tb, 0, stream>>>(Wq, WqkvT,              256, 256,  65536, 196608);
    tcvt_kernel<<<dim3(8, 8, 4),  tb, 0, stream>>>(Wk, WqkvT + 256 * 256,  256, 256,  65536, 196608);
    tcvt_kernel<<<dim3(8, 8, 4),  tb, 0, stream>>>(Wv, WqkvT + 512 * 256,  256, 256,  65536, 196608);
    tcvt_kernel<<<dim3(8, 8, 4),  tb, 0, stream>>>(Wo, WoT,                256, 256,  65536, 65536);
    tcvt_kernel<<<dim3(32, 8, 4), tb, 0, stream>>>(W1, W1T,                256, 1024, 262144, 262144);
    tcvt_kernel<<<dim3(8, 32, 4), tb, 0, stream>>>(W2, W2T,                1024, 256, 262144, 262144);
    bcat_kernel<<<4, 768, 0, stream>>>(bq, bk, bv, bqkv);

    embed_kernel<<<NT_, blk, 0, stream>>>(x, Win, b_in, h);

    for (int l = 0; l < NL_; ++l) {
        const __hip_bfloat16* wqkv = WqkvT + (size_t)l * 768 * 256;
        const __hip_bfloat16* wo   = WoT   + (size_t)l * 256 * 256;
        const __hip_bfloat16* w1   = W1T   + (size_t)l * 1024 * 256;
        const __hip_bfloat16* w2   = W2T   + (size_t)l * 256 * 1024;

        ln_kernel<<<NT_ / 4, blk, 0, stream>>>(h, lnA_s + l * D_, lnA_b + l * D_, y);

        mgemm<0><<<dim3(6, 72), blk, 0, stream>>>(y, wqkv, bqkv + l * 768, nullptr,
                                                  qkv, nullptr, NT_, 768, 256);
        attn_kernel<<<NT_, blk, 0, stream>>>(qkv, rel_emb, att);
        mgemm<1><<<dim3(2, 72), blk, 0, stream>>>(att, wo, bo + l * D_, h,
                                                  h, nullptr, NT_, 256, 256);

        ln_kernel<<<NT_ / 4, blk, 0, stream>>>(h, lnB_s + l * D_, lnB_b + l * D_, y);

        mgemm<2><<<dim3(8, 72), blk, 0, stream>>>(y, w1, b1 + l * MLP_, nullptr,
                                                  nullptr, tbuf, NT_, 1024, 256);
        mgemm<1><<<dim3(2, 72), blk, 0, stream>>>(tbuf, w2, b2 + l * D_, h,
                                                  h, nullptr, NT_, 256, 1024);
    }

    final_kernel<<<NT_, blk, 0, stream>>>(h, lnF_s, lnF_b, Wout, bout, out);
}

// Round 6
// 666.005 us; speedup vs baseline: 3.0422x; 1.1230x over previous
//
#include <hip/hip_runtime.h>
#include <hip/hip_bf16.h>
#include <math.h>

// ---- static problem dims ----
#define NT_   9216          // B*L tokens
#define D_    256
#define NH_   8
#define HD_   32
#define L_    2304
#define HH_   48
#define WW_   48
#define MLP_  1024
#define NL_   4

typedef __attribute__((ext_vector_type(8))) short bf16x8;
typedef __attribute__((ext_vector_type(4))) float f32x4;

// =====================================================================
// helpers
// =====================================================================
__device__ __forceinline__ float gelu_tanh(float x) {
    const float c0 = 0.7978845608028654f;   // sqrt(2/pi)
    const float c1 = 0.044715f;
    float u = c0 * (x + c1 * x * x * x);
    return 0.5f * x * (1.0f + tanhf(u));
}

__device__ __forceinline__ void gload16(const void* gsrc, void* ldst) {
    __builtin_amdgcn_global_load_lds(
        (const __attribute__((address_space(1))) void*)gsrc,
        (__attribute__((address_space(3))) void*)ldst, 16, 0, 0);
}

__device__ __forceinline__ unsigned short f2bf(float f) {
    __hip_bfloat16 h = __float2bfloat16(f);
    return *(unsigned short*)&h;
}

// =====================================================================
// prep: fp32 [K][N] -> bf16 [N][K] transpose+convert, batched over layers
// =====================================================================
__global__ void tcvt_kernel(const float* __restrict__ in, __hip_bfloat16* __restrict__ out,
                            int K, int N, int inLayerStride, int outLayerStride) {
    __shared__ float t[32][33];
    int l = blockIdx.z;
    int n0 = blockIdx.x * 32, k0 = blockIdx.y * 32;
    int tx = threadIdx.x, ty = threadIdx.y;
    const float* src = in + (size_t)l * inLayerStride;
    #pragma unroll
    for (int r = 0; r < 32; r += 8)
        t[ty + r][tx] = src[(size_t)(k0 + ty + r) * N + n0 + tx];
    __syncthreads();
    __hip_bfloat16* dst = out + (size_t)l * outLayerStride;
    #pragma unroll
    for (int r = 0; r < 32; r += 8)
        dst[(size_t)(n0 + ty + r) * K + k0 + tx] = __float2bfloat16(t[tx][ty + r]);
}

// concat bq|bk|bv -> bqkv[NL][768]
__global__ void bcat_kernel(const float* __restrict__ bq, const float* __restrict__ bk,
                            const float* __restrict__ bv, float* __restrict__ bqkv) {
    int l = blockIdx.x, n = threadIdx.x;
    float v = (n < 256) ? bq[l * 256 + n] : (n < 512 ? bk[l * 256 + n - 256] : bv[l * 256 + n - 512]);
    bqkv[l * 768 + n] = v;
}

// =====================================================================
// embed
// =====================================================================
__global__ void embed_kernel(const int* __restrict__ x, const float* __restrict__ Win,
                             const float* __restrict__ b_in, float* __restrict__ h) {
    int t = blockIdx.x, d = threadIdx.x;
    int l = t % L_;
    int yy = l / WW_, xx = l % WW_;
    float xv = (float)x[t];
    float yn = yy * (1.0f / 47.0f);
    float xn = xx * (1.0f / 47.0f);
    h[t * D_ + d] = xv * Win[d] + yn * Win[D_ + d] + xn * Win[2 * D_ + d] + b_in[d];
}

// =====================================================================
// LayerNorm -> bf16. One wave per token, float4 per lane, 8B bf16 stores.
// grid NT_/4 blocks x 256 threads (4 waves).
// =====================================================================
__global__ void ln_kernel(const float* __restrict__ h, const float* __restrict__ s,
                          const float* __restrict__ bb, __hip_bfloat16* __restrict__ y) {
    int wid = threadIdx.x >> 6, lane = threadIdx.x & 63;
    int t = (blockIdx.x << 2) + wid;
    float4 v = *(const float4*)(h + (size_t)t * D_ + lane * 4);
    float sum = v.x + v.y + v.z + v.w;
    float sq  = v.x * v.x + v.y * v.y + v.z * v.z + v.w * v.w;
    #pragma unroll
    for (int off = 32; off; off >>= 1) {
        sum += __shfl_xor(sum, off);
        sq  += __shfl_xor(sq,  off);
    }
    float mu  = sum * (1.0f / D_);
    float var = sq * (1.0f / D_) - mu * mu;
    float rs  = rsqrtf(var + 1e-6f);
    float4 s4 = *(const float4*)(s  + lane * 4);
    float4 b4 = *(const float4*)(bb + lane * 4);
    ushort4 o;
    o.x = f2bf((v.x - mu) * rs * s4.x + b4.x);
    o.y = f2bf((v.y - mu) * rs * s4.y + b4.y);
    o.z = f2bf((v.z - mu) * rs * s4.z + b4.z);
    o.w = f2bf((v.w - mu) * rs * s4.w + b4.w);
    *(ushort4*)(y + (size_t)t * D_ + lane * 4) = o;
}

// =====================================================================
// tiled local attention. block = 8x8 token tile x 1 head.
// Stage the 12x12 k/v halo (144 rows x 32 dims, fp32) into LDS once;
// each k/v row then serves all 25 querying neighbors from LDS instead
// of 25 separate global gathers. Torus wrap handled at staging.
// 256 threads = 8 groups of 32 lanes; group g owns tile row g (8 tokens).
// Per token: lane-per-neighbor serial dot (25 lanes live), 32-lane
// shuffle softmax (idle lanes exp->0), lane-per-dim PV. Math identical
// to the verified round-5 kernel.
// LDS rows padded to 36 floats (144 B) to spread dot-phase rows over
// banks; PV reads (32 consecutive floats per row) are conflict-free.
// grid (36 tiles, 8 heads, 4 images).
// =====================================================================
__global__ __launch_bounds__(256)
void attn_kernel(const float* __restrict__ qkv, const float* __restrict__ rel_emb,
                 __hip_bfloat16* __restrict__ att) {
    __shared__ float ks[144 * 36];
    __shared__ float vsd[144 * 36];

    const int tile = blockIdx.x;
    const int hh   = blockIdx.y;
    const int b    = blockIdx.z;
    const int ty   = tile / 6, tx = tile - ty * 6;
    const int y0   = ty * 8,  x0  = tx * 8;
    const int tid  = threadIdx.x;

    // ---- stage k and v halo: 144 rows x 32 floats each ----
    for (int idx = tid; idx < 144 * 32; idx += 256) {
        int r = idx >> 5, d = idx & 31;
        int ly = r / 12, lx = r - ly * 12;
        int gy = y0 + ly - 2; gy += (gy < 0) ? HH_ : 0; gy -= (gy >= HH_) ? HH_ : 0;
        int gx = x0 + lx - 2; gx += (gx < 0) ? WW_ : 0; gx -= (gx >= WW_) ? WW_ : 0;
        const float* row = qkv + (size_t)(b * L_ + gy * WW_ + gx) * 768 + hh * HD_;
        ks[r * 36 + d]  = row[256 + d];
        vsd[r * 36 + d] = row[512 + d];
    }
    __syncthreads();

    const int g = tid >> 5;          // group = tile row qy
    const int j = tid & 31;          // neighbor id (dot) / dim id (PV)
    const bool valid = (j < 25);
    const int oy2 = j / 5, ox2 = j - oy2 * 5;

    const float bias = rel_emb[hh * 225 + (9 - oy2) * 15 + (9 - ox2)];

    for (int s = 0; s < 8; ++s) {    // qx within tile
        const int t = b * L_ + (y0 + g) * WW_ + (x0 + s);

        // q broadcast loads (32 floats)
        const float* qp = qkv + (size_t)t * 768 + hh * HD_;
        // k row for this lane's neighbor, from LDS
        const int hr = valid ? ((g + oy2) * 12 + (s + ox2)) : 0;
        const float* kp = ks + hr * 36;

        float dot = 0.f;
        #pragma unroll
        for (int d = 0; d < 8; ++d) {
            float4 q4 = ((const float4*)qp)[d];
            float4 k4 = ((const float4*)kp)[d];
            dot += q4.x * k4.x + q4.y * k4.y + q4.z * k4.z + q4.w * k4.w;
        }
        float sc = valid ? (dot * 0.17677669529663687f + bias) : -1e30f;

        // softmax over the 32-lane group (25 live)
        float m = sc;
        #pragma unroll
        for (int off = 16; off; off >>= 1) m = fmaxf(m, __shfl_xor(m, off, 32));
        float p = __expf(sc - m);    // idle lanes -> 0
        float sum = p;
        #pragma unroll
        for (int off = 16; off; off >>= 1) sum += __shfl_xor(sum, off, 32);
        float inv = 1.0f / sum;

        // PV: lane j owns output dim j
        float acc = 0.f;
        #pragma unroll
        for (int n = 0; n < 25; ++n) {
            float pn = __shfl(p, n, 32);
            int   rn = (g + n / 5) * 12 + (s + n % 5);   // group-uniform
            acc += pn * vsd[rn * 36 + j];
        }
        att[t * D_ + hh * HD_ + j] = __float2bfloat16(acc * inv);
    }
}

// =====================================================================
// bf16 MFMA GEMM (m97 structure): C[M,N] = A[M,K] @ BT[N,K]^T + bias
// EPI: 0 = bias -> fp32; 1 = bias+res -> fp32; 2 = bias+gelu -> bf16
// =====================================================================
template<int EPI>
__global__ __launch_bounds__(256, 2)
void mgemm(const __hip_bfloat16* __restrict__ A, const __hip_bfloat16* __restrict__ BT,
           const float* __restrict__ bias, const float* res,
           float* Cf, __hip_bfloat16* Cb, int M, int N, int K) {
    __shared__ __hip_bfloat16 As[128 * 32];
    __shared__ __hip_bfloat16 Bs[128 * 32];
    const int bm = blockIdx.y * 128, bn = blockIdx.x * 128;
    const int tid = threadIdx.x, lane = tid & 63, wv = tid >> 6;
    const int wm = (wv >> 1) * 64, wn = (wv & 1) * 64;

    const __hip_bfloat16* aSrc = A + (size_t)(bm + 16 * wv + (lane >> 2)) * K + (lane & 3) * 8;
    const __hip_bfloat16* bSrc = BT + (size_t)(bn + 16 * wv + (lane >> 2)) * K + (lane & 3) * 8;
    __hip_bfloat16* aDst0 = As + wv * 512;
    __hip_bfloat16* aDst1 = As + (wv + 4) * 512;
    __hip_bfloat16* bDst0 = Bs + wv * 512;
    __hip_bfloat16* bDst1 = Bs + (wv + 4) * 512;
    const size_t rowJump = (size_t)64 * K;

    f32x4 acc[4][4];
    #pragma unroll
    for (int i = 0; i < 4; ++i)
        #pragma unroll
        for (int j = 0; j < 4; ++j)
            acc[i][j] = (f32x4){0.f, 0.f, 0.f, 0.f};

    const int rsel = (lane & 15);
    const int ko   = (lane >> 4) * 8;

    for (int k0 = 0; k0 < K; k0 += 32) {
        gload16(aSrc,            aDst0);
        gload16(aSrc + rowJump,  aDst1);
        gload16(bSrc,            bDst0);
        gload16(bSrc + rowJump,  bDst1);
        __syncthreads();

        bf16x8 af[4], bfr[4];
        #pragma unroll
        for (int f = 0; f < 4; ++f) {
            af[f]  = *(const bf16x8*)(As + (wm + f * 16 + rsel) * 32 + ko);
            bfr[f] = *(const bf16x8*)(Bs + (wn + f * 16 + rsel) * 32 + ko);
        }
        #pragma unroll
        for (int i = 0; i < 4; ++i)
            #pragma unroll
            for (int j = 0; j < 4; ++j)
                acc[i][j] = __builtin_amdgcn_mfma_f32_16x16x32_bf16(af[i], bfr[j], acc[i][j], 0, 0, 0);
        __syncthreads();
        aSrc += 32; bSrc += 32;
    }

    #pragma unroll
    for (int i = 0; i < 4; ++i) {
        #pragma unroll
        for (int r = 0; r < 4; ++r) {
            int rr = bm + wm + i * 16 + (lane >> 4) * 4 + r;
            #pragma unroll
            for (int j = 0; j < 4; ++j) {
                int cc = bn + wn + j * 16 + rsel;
                float v = acc[i][j][r] + bias[cc];
                if (EPI == 2) {
                    Cb[(size_t)rr * N + cc] = __float2bfloat16(gelu_tanh(v));
                } else {
                    if (EPI == 1) v += res[(size_t)rr * N + cc];
                    Cf[(size_t)rr * N + cc] = v;
                }
            }
        }
    }
}

// =====================================================================
// final: fused LN(lnF) + dot with Wout + bout -> logits[t]
// =====================================================================
__global__ void final_kernel(const float* __restrict__ h, const float* __restrict__ s,
                             const float* __restrict__ bb, const float* __restrict__ Wout,
                             const float* __restrict__ bout, float* __restrict__ out) {
    int t = blockIdx.x, d = threadIdx.x;
    float v = h[t * D_ + d];
    float a = v, b2 = v * v;
    #pragma unroll
    for (int off = 32; off; off >>= 1) {
        a  += __shfl_xor(a,  off);
        b2 += __shfl_xor(b2, off);
    }
    __shared__ float red[8];
    __shared__ float red2[4];
    int wave = threadIdx.x >> 6;
    if ((threadIdx.x & 63) == 0) { red[wave] = a; red[4 + wave] = b2; }
    __syncthreads();
    float sum   = red[0] + red[1] + red[2] + red[3];
    float sumsq = red[4] + red[5] + red[6] + red[7];
    float mu  = sum * (1.0f / D_);
    float var = sumsq * (1.0f / D_) - mu * mu;
    float rs  = rsqrtf(var + 1e-6f);
    float yv  = (v - mu) * rs * s[d] + bb[d];
    float p   = yv * Wout[d];
    #pragma unroll
    for (int off = 32; off; off >>= 1) p += __shfl_xor(p, off);
    if ((threadIdx.x & 63) == 0) red2[wave] = p;
    __syncthreads();
    if (threadIdx.x == 0)
        out[t] = red2[0] + red2[1] + red2[2] + red2[3] + bout[0];
}

// =====================================================================
// launch
// =====================================================================
extern "C" void kernel_launch(void* const* d_in, const int* in_sizes, int n_in,
                              void* d_out, int out_size, void* d_ws, size_t ws_size,
                              hipStream_t stream) {
    const int*   x       = (const int*)  d_in[0];
    const float* Win     = (const float*)d_in[1];
    const float* b_in    = (const float*)d_in[2];
    const float* lnA_s   = (const float*)d_in[3];
    const float* lnA_b   = (const float*)d_in[4];
    const float* Wq      = (const float*)d_in[5];
    const float* bq      = (const float*)d_in[6];
    const float* Wk      = (const float*)d_in[7];
    const float* bk      = (const float*)d_in[8];
    const float* Wv      = (const float*)d_in[9];
    const float* bv      = (const float*)d_in[10];
    const float* Wo      = (const float*)d_in[11];
    const float* bo      = (const float*)d_in[12];
    const float* lnB_s   = (const float*)d_in[13];
    const float* lnB_b   = (const float*)d_in[14];
    const float* W1      = (const float*)d_in[15];
    const float* b1      = (const float*)d_in[16];
    const float* W2      = (const float*)d_in[17];
    const float* b2      = (const float*)d_in[18];
    const float* rel_emb = (const float*)d_in[19];
    const float* lnF_s   = (const float*)d_in[20];
    const float* lnF_b   = (const float*)d_in[21];
    const float* Wout    = (const float*)d_in[22];
    const float* bout    = (const float*)d_in[23];
    float* out = (float*)d_out;

    // ---- workspace layout (float offsets) ----
    float* ws = (float*)d_ws;
    float*          h      = ws;                                   // 2359296 f
    __hip_bfloat16* y      = (__hip_bfloat16*)(ws + 2359296);      // 1179648 f
    float*          qkv    = ws + 3538944;                         // 7077888 f
    __hip_bfloat16* att    = (__hip_bfloat16*)(ws + 10616832);     // 1179648 f
    __hip_bfloat16* tbuf   = (__hip_bfloat16*)qkv;                 // overlap (qkv dead after attn)
    __hip_bfloat16* WqkvT  = (__hip_bfloat16*)(ws + 11796480);     // 4*768*256  bf16
    __hip_bfloat16* WoT    = WqkvT + 4 * 768 * 256;                // 4*256*256
    __hip_bfloat16* W1T    = WoT   + 4 * 256 * 256;                // 4*1024*256
    __hip_bfloat16* W2T    = W1T   + 4 * 1024 * 256;               // 4*256*1024
    float*          bqkv   = (float*)(W2T + 4 * 256 * 1024);       // 4*768 f

    dim3 blk(256);
    dim3 tb(32, 8);

    // ---- weight prep: transpose + bf16 convert ----
    tcvt_kernel<<<dim3(8, 8, 4),  tb, 0, stream>>>(Wq, WqkvT,              256, 256,  65536, 196608);
    tcvt_kernel<<<dim3(8, 8, 4),  tb, 0, stream>>>(Wk, WqkvT + 256 * 256,  256, 256,  65536, 196608);
    tcvt_kernel<<<dim3(8, 8, 4),  tb, 0, stream>>>(Wv, WqkvT + 512 * 256,  256, 256,  65536, 196608);
    tcvt_kernel<<<dim3(8, 8, 4),  tb, 0, stream>>>(Wo, WoT,                256, 256,  65536, 65536);
    tcvt_kernel<<<dim3(32, 8, 4), tb, 0, stream>>>(W1, W1T,                256, 1024, 262144, 262144);
    tcvt_kernel<<<dim3(8, 32, 4), tb, 0, stream>>>(W2, W2T,                1024, 256, 262144, 262144);
    bcat_kernel<<<4, 768, 0, stream>>>(bq, bk, bv, bqkv);

    embed_kernel<<<NT_, blk, 0, stream>>>(x, Win, b_in, h);

    for (int l = 0; l < NL_; ++l) {
        const __hip_bfloat16* wqkv = WqkvT + (size_t)l * 768 * 256;
        const __hip_bfloat16* wo   = WoT   + (size_t)l * 256 * 256;
        const __hip_bfloat16* w1   = W1T   + (size_t)l * 1024 * 256;
        const __hip_bfloat16* w2   = W2T   + (size_t)l * 256 * 1024;

        ln_kernel<<<NT_ / 4, blk, 0, stream>>>(h, lnA_s + l * D_, lnA_b + l * D_, y);

        mgemm<0><<<dim3(6, 72), blk, 0, stream>>>(y, wqkv, bqkv + l * 768, nullptr,
                                                  qkv, nullptr, NT_, 768, 256);
        attn_kernel<<<dim3(36, 8, 4), blk, 0, stream>>>(qkv, rel_emb, att);
        mgemm<1><<<dim3(2, 72), blk, 0, stream>>>(att, wo, bo + l * D_, h,
                                                  h, nullptr, NT_, 256, 256);

        ln_kernel<<<NT_ / 4, blk, 0, stream>>>(h, lnB_s + l * D_, lnB_b + l * D_, y);

        mgemm<2><<<dim3(8, 72), blk, 0, stream>>>(y, w1, b1 + l * MLP_, nullptr,
                                                  nullptr, tbuf, NT_, 1024, 256);
        mgemm<1><<<dim3(2, 72), blk, 0, stream>>>(tbuf, w2, b2 + l * D_, h,
                                                  h, nullptr, NT_, 256, 1024);
    }

    final_kernel<<<NT_, blk, 0, stream>>>(h, lnF_s, lnF_b, Wout, bout, out);
}

// Round 8
// 631.926 us; speedup vs baseline: 3.2062x; 1.0539x over previous
//
#include <hip/hip_runtime.h>
#include <hip/hip_bf16.h>
#include <math.h>

// ---- static problem dims ----
#define NT_   9216          // B*L tokens
#define D_    256
#define NH_   8
#define HD_   32
#define L_    2304
#define HH_   48
#define WW_   48
#define MLP_  1024
#define NL_   4

typedef __attribute__((ext_vector_type(8))) short bf16x8;
typedef __attribute__((ext_vector_type(4))) float f32x4;

// =====================================================================
// helpers
// =====================================================================
__device__ __forceinline__ float gelu_tanh(float x) {
    const float c0 = 0.7978845608028654f;   // sqrt(2/pi)
    const float c1 = 0.044715f;
    float u = c0 * (x + c1 * x * x * x);
    return 0.5f * x * (1.0f + tanhf(u));
}

__device__ __forceinline__ void gload16(const void* gsrc, void* ldst) {
    __builtin_amdgcn_global_load_lds(
        (const __attribute__((address_space(1))) void*)gsrc,
        (__attribute__((address_space(3))) void*)ldst, 16, 0, 0);
}

__device__ __forceinline__ unsigned short f2bf(float f) {
    __hip_bfloat16 h = __float2bfloat16(f);
    return *(unsigned short*)&h;
}

// =====================================================================
// prep: ALL weight transposes (fp32 [K][N] -> bf16 [N][K]) + bias concat
// in ONE kernel. blocks 0..3071: one 32x32 tile each; 3072..3075: bcat.
// Per layer (768 tiles): [0,64)Wq [64,128)Wk [128,192)Wv [192,256)Wo
//                        [256,512)W1 [512,768)W2
// =====================================================================
__global__ void prep_kernel(const float* __restrict__ Wq, const float* __restrict__ Wk,
                            const float* __restrict__ Wv, const float* __restrict__ Wo,
                            const float* __restrict__ W1, const float* __restrict__ W2,
                            const float* __restrict__ bq, const float* __restrict__ bk,
                            const float* __restrict__ bv,
                            __hip_bfloat16* __restrict__ WqkvT, __hip_bfloat16* __restrict__ WoT,
                            __hip_bfloat16* __restrict__ W1T, __hip_bfloat16* __restrict__ W2T,
                            float* __restrict__ bqkv) {
    int bid = blockIdx.x;
    int tid = threadIdx.y * 32 + threadIdx.x;
    if (bid >= 3072) {                       // bias concat
        int l = bid - 3072;
        for (int n = tid; n < 768; n += 256) {
            float v = (n < 256) ? bq[l * 256 + n]
                    : (n < 512 ? bk[l * 256 + n - 256] : bv[l * 256 + n - 512]);
            bqkv[l * 768 + n] = v;
        }
        return;
    }
    int l = bid / 768, rem = bid - l * 768;
    const float* src; __hip_bfloat16* dst;
    int K, N, n0, k0;
    if (rem < 256) {                         // 256x256 weights, 8x8 tiles
        int which = rem >> 6, tidx = rem & 63;
        n0 = (tidx & 7) * 32; k0 = (tidx >> 3) * 32;
        K = 256; N = 256;
        if (which == 0)      { src = Wq + (size_t)l * 65536; dst = WqkvT + (size_t)l * 196608; }
        else if (which == 1) { src = Wk + (size_t)l * 65536; dst = WqkvT + (size_t)l * 196608 + 65536; }
        else if (which == 2) { src = Wv + (size_t)l * 65536; dst = WqkvT + (size_t)l * 196608 + 131072; }
        else                 { src = Wo + (size_t)l * 65536; dst = WoT   + (size_t)l * 65536; }
    } else if (rem < 512) {                  // W1: K=256,N=1024, 32x8 tiles
        int tidx = rem - 256;
        n0 = (tidx & 31) * 32; k0 = (tidx >> 5) * 32;
        K = 256; N = 1024;
        src = W1 + (size_t)l * 262144; dst = W1T + (size_t)l * 262144;
    } else {                                 // W2: K=1024,N=256, 8x32 tiles
        int tidx = rem - 512;
        n0 = (tidx & 7) * 32; k0 = (tidx >> 3) * 32;
        K = 1024; N = 256;
        src = W2 + (size_t)l * 262144; dst = W2T + (size_t)l * 262144;
    }
    __shared__ float t[32][33];
    int tx = threadIdx.x, ty = threadIdx.y;
    #pragma unroll
    for (int r = 0; r < 32; r += 8)
        t[ty + r][tx] = src[(size_t)(k0 + ty + r) * N + n0 + tx];
    __syncthreads();
    #pragma unroll
    for (int r = 0; r < 32; r += 8)
        dst[(size_t)(n0 + ty + r) * K + k0 + tx] = __float2bfloat16(t[tx][ty + r]);
}

// =====================================================================
// embed
// =====================================================================
__global__ void embed_kernel(const int* __restrict__ x, const float* __restrict__ Win,
                             const float* __restrict__ b_in, float* __restrict__ h) {
    int t = blockIdx.x, d = threadIdx.x;
    int l = t % L_;
    int yy = l / WW_, xx = l % WW_;
    float xv = (float)x[t];
    float yn = yy * (1.0f / 47.0f);
    float xn = xx * (1.0f / 47.0f);
    h[t * D_ + d] = xv * Win[d] + yn * Win[D_ + d] + xn * Win[2 * D_ + d] + b_in[d];
}

// =====================================================================
// LayerNorm -> bf16. One wave per token, float4 per lane, 8B bf16 stores.
// grid NT_/4 blocks x 256 threads (4 waves).
// =====================================================================
__global__ void ln_kernel(const float* __restrict__ h, const float* __restrict__ s,
                          const float* __restrict__ bb, __hip_bfloat16* __restrict__ y) {
    int wid = threadIdx.x >> 6, lane = threadIdx.x & 63;
    int t = (blockIdx.x << 2) + wid;
    float4 v = *(const float4*)(h + (size_t)t * D_ + lane * 4);
    float sum = v.x + v.y + v.z + v.w;
    float sq  = v.x * v.x + v.y * v.y + v.z * v.z + v.w * v.w;
    #pragma unroll
    for (int off = 32; off; off >>= 1) {
        sum += __shfl_xor(sum, off);
        sq  += __shfl_xor(sq,  off);
    }
    float mu  = sum * (1.0f / D_);
    float var = sq * (1.0f / D_) - mu * mu;
    float rs  = rsqrtf(var + 1e-6f);
    float4 s4 = *(const float4*)(s  + lane * 4);
    float4 b4 = *(const float4*)(bb + lane * 4);
    ushort4 o;
    o.x = f2bf((v.x - mu) * rs * s4.x + b4.x);
    o.y = f2bf((v.y - mu) * rs * s4.y + b4.y);
    o.z = f2bf((v.z - mu) * rs * s4.z + b4.z);
    o.w = f2bf((v.w - mu) * rs * s4.w + b4.w);
    *(ushort4*)(y + (size_t)t * D_ + lane * 4) = o;
}

// =====================================================================
// tiled local attention. block = 8x8 token tile x 1 head.
// 12x12 k/v halo staged into LDS once (float4-vectorized), then the
// verified lane-per-neighbor pipeline per token. grid (36, 8, 4).
// =====================================================================
__global__ __launch_bounds__(256)
void attn_kernel(const float* __restrict__ qkv, const float* __restrict__ rel_emb,
                 __hip_bfloat16* __restrict__ att) {
    __shared__ float ks[144 * 36];
    __shared__ float vsd[144 * 36];

    const int tile = blockIdx.x;
    const int hh   = blockIdx.y;
    const int b    = blockIdx.z;
    const int ty   = tile / 6, tx = tile - ty * 6;
    const int y0   = ty * 8,  x0  = tx * 8;
    const int tid  = threadIdx.x;

    // ---- stage k and v halo: 144 rows x 8 float4 chunks each ----
    for (int idx = tid; idx < 144 * 8; idx += 256) {
        int r = idx >> 3, c = (idx & 7) * 4;
        int ly = r / 12, lx = r - ly * 12;
        int gy = y0 + ly - 2; gy += (gy < 0) ? HH_ : 0; gy -= (gy >= HH_) ? HH_ : 0;
        int gx = x0 + lx - 2; gx += (gx < 0) ? WW_ : 0; gx -= (gx >= WW_) ? WW_ : 0;
        const float* row = qkv + (size_t)(b * L_ + gy * WW_ + gx) * 768 + hh * HD_ + c;
        *(float4*)(ks  + r * 36 + c) = *(const float4*)(row + 256);
        *(float4*)(vsd + r * 36 + c) = *(const float4*)(row + 512);
    }
    __syncthreads();

    const int g = tid >> 5;          // group = tile row qy
    const int j = tid & 31;          // neighbor id (dot) / dim id (PV)
    const bool valid = (j < 25);
    const int oy2 = j / 5, ox2 = j - oy2 * 5;

    const float bias = rel_emb[hh * 225 + (9 - oy2) * 15 + (9 - ox2)];

    for (int s = 0; s < 8; ++s) {    // qx within tile
        const int t = b * L_ + (y0 + g) * WW_ + (x0 + s);

        const float* qp = qkv + (size_t)t * 768 + hh * HD_;
        const int hr = valid ? ((g + oy2) * 12 + (s + ox2)) : 0;
        const float* kp = ks + hr * 36;

        float dot = 0.f;
        #pragma unroll
        for (int d = 0; d < 8; ++d) {
            float4 q4 = ((const float4*)qp)[d];
            float4 k4 = ((const float4*)kp)[d];
            dot += q4.x * k4.x + q4.y * k4.y + q4.z * k4.z + q4.w * k4.w;
        }
        float sc = valid ? (dot * 0.17677669529663687f + bias) : -1e30f;

        float m = sc;
        #pragma unroll
        for (int off = 16; off; off >>= 1) m = fmaxf(m, __shfl_xor(m, off, 32));
        float p = __expf(sc - m);    // idle lanes -> 0
        float sum = p;
        #pragma unroll
        for (int off = 16; off; off >>= 1) sum += __shfl_xor(sum, off, 32);
        float inv = 1.0f / sum;

        float acc = 0.f;
        #pragma unroll
        for (int n = 0; n < 25; ++n) {
            float pn = __shfl(p, n, 32);
            int   rn = (g + n / 5) * 12 + (s + n % 5);   // group-uniform
            acc += pn * vsd[rn * 36 + j];
        }
        att[t * D_ + hh * HD_ + j] = __float2bfloat16(acc * inv);
    }
}

// =====================================================================
// bf16 MFMA GEMM (m97 structure) + XCD-aware bijective tile remap.
// Consecutive dispatch-linear blocks round-robin XCDs; remapping gives
// each XCD a contiguous tile chunk so A/B panel re-reads hit its own L2.
// Requires gridDim.x*gridDim.y % 8 == 0 (all our grids: 432/144/576).
// EPI: 0 = bias -> fp32; 1 = bias+res -> fp32; 2 = bias+gelu -> bf16
// =====================================================================
template<int EPI>
__global__ __launch_bounds__(256, 2)
void mgemm(const __hip_bfloat16* __restrict__ A, const __hip_bfloat16* __restrict__ BT,
           const float* __restrict__ bias, const float* res,
           float* Cf, __hip_bfloat16* Cb, int M, int N, int K) {
    __shared__ __hip_bfloat16 As[128 * 32];
    __shared__ __hip_bfloat16 Bs[128 * 32];

    // XCD-aware remap (bijective: nwg % 8 == 0)
    const int nwg = gridDim.x * gridDim.y;
    const int cpx = nwg >> 3;
    const int lin = blockIdx.y * gridDim.x + blockIdx.x;   // dispatch order (x fastest)
    const int tile = (lin & 7) * cpx + (lin >> 3);
    const int bm = (tile / gridDim.x) * 128;
    const int bn = (tile % gridDim.x) * 128;

    const int tid = threadIdx.x, lane = tid & 63, wv = tid >> 6;
    const int wm = (wv >> 1) * 64, wn = (wv & 1) * 64;

    const __hip_bfloat16* aSrc = A + (size_t)(bm + 16 * wv + (lane >> 2)) * K + (lane & 3) * 8;
    const __hip_bfloat16* bSrc = BT + (size_t)(bn + 16 * wv + (lane >> 2)) * K + (lane & 3) * 8;
    __hip_bfloat16* aDst0 = As + wv * 512;
    __hip_bfloat16* aDst1 = As + (wv + 4) * 512;
    __hip_bfloat16* bDst0 = Bs + wv * 512;
    __hip_bfloat16* bDst1 = Bs + (wv + 4) * 512;
    const size_t rowJump = (size_t)64 * K;

    f32x4 acc[4][4];
    #pragma unroll
    for (int i = 0; i < 4; ++i)
        #pragma unroll
        for (int j = 0; j < 4; ++j)
            acc[i][j] = (f32x4){0.f, 0.f, 0.f, 0.f};

    const int rsel = (lane & 15);
    const int ko   = (lane >> 4) * 8;

    for (int k0 = 0; k0 < K; k0 += 32) {
        gload16(aSrc,            aDst0);
        gload16(aSrc + rowJump,  aDst1);
        gload16(bSrc,            bDst0);
        gload16(bSrc + rowJump,  bDst1);
        __syncthreads();

        bf16x8 af[4], bfr[4];
        #pragma unroll
        for (int f = 0; f < 4; ++f) {
            af[f]  = *(const bf16x8*)(As + (wm + f * 16 + rsel) * 32 + ko);
            bfr[f] = *(const bf16x8*)(Bs + (wn + f * 16 + rsel) * 32 + ko);
        }
        #pragma unroll
        for (int i = 0; i < 4; ++i)
            #pragma unroll
            for (int j = 0; j < 4; ++j)
                acc[i][j] = __builtin_amdgcn_mfma_f32_16x16x32_bf16(af[i], bfr[j], acc[i][j], 0, 0, 0);
        __syncthreads();
        aSrc += 32; bSrc += 32;
    }

    #pragma unroll
    for (int i = 0; i < 4; ++i) {
        #pragma unroll
        for (int r = 0; r < 4; ++r) {
            int rr = bm + wm + i * 16 + (lane >> 4) * 4 + r;
            #pragma unroll
            for (int j = 0; j < 4; ++j) {
                int cc = bn + wn + j * 16 + rsel;
                float v = acc[i][j][r] + bias[cc];
                if (EPI == 2) {
                    Cb[(size_t)rr * N + cc] = __float2bfloat16(gelu_tanh(v));
                } else {
                    if (EPI == 1) v += res[(size_t)rr * N + cc];
                    Cf[(size_t)rr * N + cc] = v;
                }
            }
        }
    }
}

// =====================================================================
// final: fused LN(lnF) + dot with Wout + bout -> logits[t]
// =====================================================================
__global__ void final_kernel(const float* __restrict__ h, const float* __restrict__ s,
                             const float* __restrict__ bb, const float* __restrict__ Wout,
                             const float* __restrict__ bout, float* __restrict__ out) {
    int t = blockIdx.x, d = threadIdx.x;
    float v = h[t * D_ + d];
    float a = v, b2 = v * v;
    #pragma unroll
    for (int off = 32; off; off >>= 1) {
        a  += __shfl_xor(a,  off);
        b2 += __shfl_xor(b2, off);
    }
    __shared__ float red[8];
    __shared__ float red2[4];
    int wave = threadIdx.x >> 6;
    if ((threadIdx.x & 63) == 0) { red[wave] = a; red[4 + wave] = b2; }
    __syncthreads();
    float sum   = red[0] + red[1] + red[2] + red[3];
    float sumsq = red[4] + red[5] + red[6] + red[7];
    float mu  = sum * (1.0f / D_);
    float var = sumsq * (1.0f / D_) - mu * mu;
    float rs  = rsqrtf(var + 1e-6f);
    float yv  = (v - mu) * rs * s[d] + bb[d];
    float p   = yv * Wout[d];
    #pragma unroll
    for (int off = 32; off; off >>= 1) p += __shfl_xor(p, off);
    if ((threadIdx.x & 63) == 0) red2[wave] = p;
    __syncthreads();
    if (threadIdx.x == 0)
        out[t] = red2[0] + red2[1] + red2[2] + red2[3] + bout[0];
}

// =====================================================================
// launch
// =====================================================================
extern "C" void kernel_launch(void* const* d_in, const int* in_sizes, int n_in,
                              void* d_out, int out_size, void* d_ws, size_t ws_size,
                              hipStream_t stream) {
    const int*   x       = (const int*)  d_in[0];
    const float* Win     = (const float*)d_in[1];
    const float* b_in    = (const float*)d_in[2];
    const float* lnA_s   = (const float*)d_in[3];
    const float* lnA_b   = (const float*)d_in[4];
    const float* Wq      = (const float*)d_in[5];
    const float* bq      = (const float*)d_in[6];
    const float* Wk      = (const float*)d_in[7];
    const float* bk      = (const float*)d_in[8];
    const float* Wv      = (const float*)d_in[9];
    const float* bv      = (const float*)d_in[10];
    const float* Wo      = (const float*)d_in[11];
    const float* bo      = (const float*)d_in[12];
    const float* lnB_s   = (const float*)d_in[13];
    const float* lnB_b   = (const float*)d_in[14];
    const float* W1      = (const float*)d_in[15];
    const float* b1      = (const float*)d_in[16];
    const float* W2      = (const float*)d_in[17];
    const float* b2      = (const float*)d_in[18];
    const float* rel_emb = (const float*)d_in[19];
    const float* lnF_s   = (const float*)d_in[20];
    const float* lnF_b   = (const float*)d_in[21];
    const float* Wout    = (const float*)d_in[22];
    const float* bout    = (const float*)d_in[23];
    float* out = (float*)d_out;

    // ---- workspace layout (float offsets) ----
    float* ws = (float*)d_ws;
    float*          h      = ws;                                   // 2359296 f
    __hip_bfloat16* y      = (__hip_bfloat16*)(ws + 2359296);      // 1179648 f
    float*          qkv    = ws + 3538944;                         // 7077888 f
    __hip_bfloat16* att    = (__hip_bfloat16*)(ws + 10616832);     // 1179648 f
    __hip_bfloat16* tbuf   = (__hip_bfloat16*)qkv;                 // overlap (qkv dead after attn)
    __hip_bfloat16* WqkvT  = (__hip_bfloat16*)(ws + 11796480);     // 4*768*256  bf16
    __hip_bfloat16* WoT    = WqkvT + 4 * 768 * 256;                // 4*256*256
    __hip_bfloat16* W1T    = WoT   + 4 * 256 * 256;                // 4*1024*256
    __hip_bfloat16* W2T    = W1T   + 4 * 1024 * 256;               // 4*256*1024
    float*          bqkv   = (float*)(W2T + 4 * 256 * 1024);       // 4*768 f

    dim3 blk(256);

    // ---- weight prep: single kernel (transpose+convert+bias concat) ----
    prep_kernel<<<3076, dim3(32, 8), 0, stream>>>(Wq, Wk, Wv, Wo, W1, W2,
                                                  bq, bk, bv,
                                                  WqkvT, WoT, W1T, W2T, bqkv);

    embed_kernel<<<NT_, blk, 0, stream>>>(x, Win, b_in, h);

    for (int l = 0; l < NL_; ++l) {
        const __hip_bfloat16* wqkv = WqkvT + (size_t)l * 768 * 256;
        const __hip_bfloat16* wo   = WoT   + (size_t)l * 256 * 256;
        const __hip_bfloat16* w1   = W1T   + (size_t)l * 1024 * 256;
        const __hip_bfloat16* w2   = W2T   + (size_t)l * 256 * 1024;

        ln_kernel<<<NT_ / 4, blk, 0, stream>>>(h, lnA_s + l * D_, lnA_b + l * D_, y);

        mgemm<0><<<dim3(6, 72), blk, 0, stream>>>(y, wqkv, bqkv + l * 768, nullptr,
                                                  qkv, nullptr, NT_, 768, 256);
        attn_kernel<<<dim3(36, 8, 4), blk, 0, stream>>>(qkv, rel_emb, att);
        mgemm<1><<<dim3(2, 72), blk, 0, stream>>>(att, wo, bo + l * D_, h,
                                                  h, nullptr, NT_, 256, 256);

        ln_kernel<<<NT_ / 4, blk, 0, stream>>>(h, lnB_s + l * D_, lnB_b + l * D_, y);

        mgemm<2><<<dim3(8, 72), blk, 0, stream>>>(y, w1, b1 + l * MLP_, nullptr,
                                                  nullptr, tbuf, NT_, 1024, 256);
        mgemm<1><<<dim3(2, 72), blk, 0, stream>>>(tbuf, w2, b2 + l * D_, h,
                                                  h, nullptr, NT_, 256, 1024);
    }

    final_kernel<<<NT_, blk, 0, stream>>>(h, lnF_s, lnF_b, Wout, bout, out);
}